// Round 3
// baseline (173.409 us; speedup 1.0000x reference)
//
#include <hip/hip_runtime.h>

// Problem constants (fixed by setup_inputs)
#define HW   256
#define Pp   33
#define PPAD 36        // padded patch row (ushort units)
#define OUTF 128
#define SIG  16

// conv1-output plane (bf16) for conv2 MFMA A-operands:
// [rowslot 6][parity 2][col' 16][kc 40] ushort.
#define KCP   40
#define PLROW (2 * 16 * KCP)
#define PLSZ  (6 * PLROW)        // 7680 shorts
#define IMS   40                 // im2col k-stride (shorts); 80B rows, b128-aligned

// ws layout (float offsets)
#define WS_W1FH 0       // [2 nt][64 lane][8 j] ushort = 512 f (conv1 B-frags hi)
#define WS_W1FL 512     // same, lo
#define WS_BHI  1024    // 18432 ushort = 9216 f (conv2 B-frags hi)
#define WS_BLO  10240   // conv2 B-frags lo
#define WS_WLT  19456   // [64][128] f32 = 8192 (wl transposed, for loss kernel)
#define WS_GAPS 27648   // [1024 nb][2 side][64 ch] f32 = 131072 (exact gap/225)

typedef __attribute__((ext_vector_type(8))) short v8s;    // 8 bf16
typedef __attribute__((ext_vector_type(4))) float f32x4;  // MFMA acc

__device__ __forceinline__ unsigned short f2bf_rne(float x) {
  unsigned u = __float_as_uint(x);
  unsigned r = (u + 0x7FFFu + ((u >> 16) & 1u)) >> 16;
  return (unsigned short)r;
}
__device__ __forceinline__ float bf2f(unsigned short h) {
  return __uint_as_float(((unsigned)h) << 16);
}

__global__ __launch_bounds__(256) void prep_kernel(
    const float* __restrict__ w1, const float* __restrict__ w2,
    const float* __restrict__ wl, float* __restrict__ ws,
    float* __restrict__ out) {
  int t = blockIdx.x * 256 + threadIdx.x;
  int stride = gridDim.x * 256;
  if (blockIdx.x == 0 && threadIdx.x == 0) out[0] = 0.0f;
  // conv1 B-frags: k = 8*(l>>4)+j (27-dim padded to 32), ch = 16*nt + (l&15)
  unsigned short* w1h = (unsigned short*)(ws + WS_W1FH);
  unsigned short* w1lo = (unsigned short*)(ws + WS_W1FL);
  for (int i = t; i < 1024; i += stride) {
    int j  = i & 7;
    int l  = (i >> 3) & 63;
    int nt = i >> 9;
    int k  = 8 * (l >> 4) + j;
    int ch = 16 * nt + (l & 15);
    float v = (k < 27) ? w1[ch * 27 + k] : 0.0f;
    unsigned short h = f2bf_rne(v);
    w1h[i]  = h;
    w1lo[i] = f2bf_rne(v - bf2f(h));
  }
  // conv2 B-frags: n(ch)=w*16+(l&15), k(kc)=(l>>4)*8+j, per tap
  unsigned short* bhi = (unsigned short*)(ws + WS_BHI);
  unsigned short* blo = (unsigned short*)(ws + WS_BLO);
  for (int i = t; i < 18432; i += stride) {
    int j  = i & 7;
    int l  = (i >> 3) & 63;
    int w  = (i >> 9) & 3;
    int tp = i >> 11;
    int ch = w * 16 + (l & 15);
    int kc = ((l >> 4) << 3) + j;
    int ky = tp / 3, kx = tp - ky * 3;
    float v = w2[ch * 288 + kc * 9 + ky * 3 + kx];
    unsigned short h = f2bf_rne(v);
    bhi[i] = h;
    blo[i] = f2bf_rne(v - bf2f(h));
  }
  for (int i = t; i < 8192; i += stride) {
    int o = i & 127, ii = i >> 7;
    ws[WS_WLT + i] = wl[o * 64 + ii];
  }
}

// One block per (side, n, b); grid 2048. Computes the GAP vector (64 ch) of
// one patch and stores gap/225 (exact f32, plain store) to ws[WS_GAPS].
// NUMERICS ARE OP-IDENTICAL to the verified baseline: single chained MFMA
// accumulator in conv1 (hi then lo) and conv2 (tap order 0..8, hi then lo),
// same gapAcc order, same /225 scaling. Only the *schedule* differs:
//  - side-split: per-block serial path halved, 8 blocks/CU queued (5 resident)
//  - 2 barriers per y2 (was 3): sync; conv2; build; sync; conv1
//    (hiP read slots {s0..s0+2} and write slots {s0+4,s0+5} disjoint mod 6)
//  - conv2 ky=0 A-operands register-cached from previous iter's ky=2 loads
//    (ds_read_b128 per y2: 9 -> 6); registers immune to hiP slot reuse
__global__ __launch_bounds__(256) void patch_cnn_kernel(
    const float* __restrict__ imgG, const float* __restrict__ imgS,
    const float* __restrict__ kpG,  const float* __restrict__ kpS,
    const float* __restrict__ b1g,  const float* __restrict__ b2g,
    float* __restrict__ ws) {
  __shared__ __align__(16) unsigned short patch[3 * Pp * PPAD];  // 7128 B
  __shared__ __align__(16) unsigned short imcol[2][32 * IMS];    // 5120 B
  __shared__ __align__(16) unsigned short hiP[PLSZ];             // 15360 B
  // total ~27.6 KB -> 5 blocks/CU by LDS

  const int bid  = blockIdx.x;          // grid 2048
  const int side = bid & 1;
  const int nb   = bid >> 1;            // 0..1023
  const int n    = nb >> 2;
  const int b    = nb & 3;
  const int tid  = threadIdx.x;
  const int wave = tid >> 6;
  const int lane = tid & 63;

  const int m16 = lane & 15;
  const int qq  = lane >> 4;
  const int mt  = wave & 1;             // conv1 M-tile
  const int nt  = wave >> 1;            // conv1 N-tile

  // im2col build roles: thread = m(32) x k-quad(8)
  const int bm = tid & 31;
  const int kq = tid >> 5;
  int  boff[4];
  bool bval[4];
#pragma unroll
  for (int j = 0; j < 4; ++j) {
    int k = 4 * kq + j;
    bval[j] = (k < 27);
    int kk = bval[j] ? k : 0;
    int ci = kk / 9, r2 = kk - ci * 9, ky = r2 / 3, kx = r2 - ky * 3;
    boff[j] = (ci * Pp + ky) * PPAD + bm + kx;    // + r*PPAD at use
  }

  // conv1 B-frags -> registers (8 VGPRs each), bias per lane
  const v8s w1hF = ((const v8s*)((const unsigned short*)(ws + WS_W1FH)))[nt * 64 + lane];
  const v8s w1lF = ((const v8s*)((const unsigned short*)(ws + WS_W1FL)))[nt * 64 + lane];
  const float b1v = b1g[nt * 16 + m16];

  // conv2 frag pointers (global, L2-resident) and bias
  const v8s* bhW = (const v8s*)((const unsigned short*)(ws + WS_BHI)) + (wave * 64 + lane);
  const v8s* blW = (const v8s*)((const unsigned short*)(ws + WS_BLO)) + (wave * 64 + lane);
  const float b2v = b2g[wave * 16 + m16];

  auto build_row = [&](int r, int ibuf) {
    unsigned short h[4];
#pragma unroll
    for (int j = 0; j < 4; ++j)
      h[j] = bval[j] ? patch[boff[j] + r * PPAD] : (unsigned short)0;
    unsigned w0 = (unsigned)h[0] | ((unsigned)h[1] << 16);
    unsigned w1_ = (unsigned)h[2] | ((unsigned)h[3] << 16);
    *(uint2*)&imcol[ibuf][bm * IMS + 4 * kq] = make_uint2(w0, w1_);
  };

  auto conv1_row = [&](int ibuf, int sl) {
    v8s af = *(const v8s*)&imcol[ibuf][(16 * mt + m16) * IMS + 8 * qq];
    f32x4 a1 = {0.f, 0.f, 0.f, 0.f};
    a1 = __builtin_amdgcn_mfma_f32_16x16x32_bf16(af, w1hF, a1, 0, 0, 0);
    a1 = __builtin_amdgcn_mfma_f32_16x16x32_bf16(af, w1lF, a1, 0, 0, 0);
#pragma unroll
    for (int rg = 0; rg < 4; ++rg) {
      int x = 16 * mt + 4 * qq + rg;      // pixel col (x=31 garbage, unread slot)
      float f = fmaxf(a1[rg] + b1v, 0.f);
      hiP[((sl * 2 + (x & 1)) * 16 + (x >> 1)) * KCP + 16 * nt + m16] = f2bf_rne(f);
    }
  };

  // conv2 A-operand load: (row-slot sk, tap kx)
  auto ldA = [&](int sk, int kx) -> v8s {
    const int p = kx & 1;
    int cp = m16 + (kx >> 1); if (cp > 15) cp = 15;   // xo=15 is pad, discarded
    return *(const v8s*)&hiP[((sk * 2 + p) * 16 + cp) * KCP + qq * 8];
  };

  const float* img = side ? imgS : imgG;
  const float* kp  = side ? kpS : kpG;

  int sx = (int)floorf(kp[n * 2 + 0] * 256.0f) - SIG;
  int sy = (int)floorf(kp[n * 2 + 1] * 256.0f) - SIG;
  sx = min(max(sx, 0), HW - Pp);
  sy = min(max(sy, 0), HW - Pp);

  // stage patch as bf16 pairs (coalesced float2 global reads)
  for (int i = tid; i < (3 * Pp * PPAD) / 2; i += 256) {
    int e  = 2 * i;
    int ci = e / (Pp * PPAD);
    int r2 = e - ci * (Pp * PPAD);
    int r  = r2 / PPAD;
    int cc = r2 - r * PPAD;
    float vx = 0.f, vy = 0.f;
    const float* rowp = &img[((b * 3 + ci) * HW + (sy + r)) * HW + sx];
    if (cc < 32) { float2 v = *(const float2*)(rowp + cc); vx = v.x; vy = v.y; }
    else if (cc == 32) { vx = rowp[32]; }
    unsigned pk = (unsigned)f2bf_rne(vx) | ((unsigned)f2bf_rne(vy) << 16);
    *(unsigned*)&patch[e] = pk;
  }
  __syncthreads();                      // patch visible
  // prologue: rows 0..3 -> slots 0..3 (ibuf is ALWAYS 0/1; slot = row here)
  build_row(0, 0); build_row(1, 1);
  __syncthreads();                      // imcol visible
  conv1_row(0, 0); conv1_row(1, 1);
  __syncthreads();                      // conv1 imcol reads done before rebuild
  build_row(2, 0); build_row(3, 1);
  __syncthreads();
  conv1_row(0, 2); conv1_row(1, 3);

  float gapAcc = 0.0f;
  int s0 = 0;
  v8s c0, c1, c2;                       // cached ky-row operands (next ky=0)

#pragma unroll 1
  for (int y2 = 0; y2 < 15; ++y2) {
    __syncthreads();                    // hiP s0..s0+2 ready; imcol reads done
    if (y2 == 0) { c0 = ldA(0, 0); c1 = ldA(0, 1); c2 = ldA(0, 2); }
    f32x4 acc = {0.f, 0.f, 0.f, 0.f};
    // ky = 0 (from register cache) — tap order 0,1,2 with hi then lo (baseline order)
    acc = __builtin_amdgcn_mfma_f32_16x16x32_bf16(c0, bhW[0 * 256], acc, 0, 0, 0);
    acc = __builtin_amdgcn_mfma_f32_16x16x32_bf16(c0, blW[0 * 256], acc, 0, 0, 0);
    acc = __builtin_amdgcn_mfma_f32_16x16x32_bf16(c1, bhW[1 * 256], acc, 0, 0, 0);
    acc = __builtin_amdgcn_mfma_f32_16x16x32_bf16(c1, blW[1 * 256], acc, 0, 0, 0);
    acc = __builtin_amdgcn_mfma_f32_16x16x32_bf16(c2, bhW[2 * 256], acc, 0, 0, 0);
    acc = __builtin_amdgcn_mfma_f32_16x16x32_bf16(c2, blW[2 * 256], acc, 0, 0, 0);
    // ky = 1
    {
      int sk1 = s0 + 1; if (sk1 >= 6) sk1 -= 6;
      v8s a0 = ldA(sk1, 0), a1 = ldA(sk1, 1), a2 = ldA(sk1, 2);
      acc = __builtin_amdgcn_mfma_f32_16x16x32_bf16(a0, bhW[3 * 256], acc, 0, 0, 0);
      acc = __builtin_amdgcn_mfma_f32_16x16x32_bf16(a0, blW[3 * 256], acc, 0, 0, 0);
      acc = __builtin_amdgcn_mfma_f32_16x16x32_bf16(a1, bhW[4 * 256], acc, 0, 0, 0);
      acc = __builtin_amdgcn_mfma_f32_16x16x32_bf16(a1, blW[4 * 256], acc, 0, 0, 0);
      acc = __builtin_amdgcn_mfma_f32_16x16x32_bf16(a2, bhW[5 * 256], acc, 0, 0, 0);
      acc = __builtin_amdgcn_mfma_f32_16x16x32_bf16(a2, blW[5 * 256], acc, 0, 0, 0);
    }
    // ky = 2 -> refill cache (becomes next iteration's ky=0 row)
    {
      int sk2 = s0 + 2; if (sk2 >= 6) sk2 -= 6;
      c0 = ldA(sk2, 0); c1 = ldA(sk2, 1); c2 = ldA(sk2, 2);
      acc = __builtin_amdgcn_mfma_f32_16x16x32_bf16(c0, bhW[6 * 256], acc, 0, 0, 0);
      acc = __builtin_amdgcn_mfma_f32_16x16x32_bf16(c0, blW[6 * 256], acc, 0, 0, 0);
      acc = __builtin_amdgcn_mfma_f32_16x16x32_bf16(c1, bhW[7 * 256], acc, 0, 0, 0);
      acc = __builtin_amdgcn_mfma_f32_16x16x32_bf16(c1, blW[7 * 256], acc, 0, 0, 0);
      acc = __builtin_amdgcn_mfma_f32_16x16x32_bf16(c2, bhW[8 * 256], acc, 0, 0, 0);
      acc = __builtin_amdgcn_mfma_f32_16x16x32_bf16(c2, blW[8 * 256], acc, 0, 0, 0);
    }

    const int r0 = 2 * y2 + 4;
    if (r0 <= 30) { build_row(r0, 0); build_row(min(r0 + 1, 30), 1); }
    __syncthreads();                    // imcol visible (all waves past conv2)
    if (r0 <= 30) {
      int sl = r0 % 6;                  // r0 even -> sl in {0,2,4}, sl+1 <= 5
      conv1_row(0, sl); conv1_row(1, sl + 1);
    }

    {
      float s = fmaxf(acc.x + b2v, 0.f) + fmaxf(acc.y + b2v, 0.f) +
                fmaxf(acc.z + b2v, 0.f);
      if (qq < 3) s += fmaxf(acc.w + b2v, 0.f);   // xo=15 is pad
      gapAcc += s;
    }
    s0 += 2; if (s0 >= 6) s0 -= 6;
  }

  // reduce gapAcc over kc-quads; plain store of exact gap/225 (no atomics)
  gapAcc += __shfl_down(gapAcc, 32, 64);
  gapAcc += __shfl_down(gapAcc, 16, 64);
  if (lane < 16)
    ws[WS_GAPS + (nb * 2 + side) * 64 + wave * 16 + m16] = gapAcc * (1.0f / 225.0f);
}

// One block per (n,b) pair: replays the baseline epilogue op-for-op:
// f_side = bl[o] + fmaf-chain(gap_side[i], wlT[i][o]); d = fS - fG; dd = d^2;
// identical shfl tree; one atomicAdd of s/131072 per pair (1024 total, same
// as the verified baseline).
__global__ __launch_bounds__(128) void loss_kernel(
    const float* __restrict__ ws, const float* __restrict__ blg,
    float* __restrict__ out) {
  __shared__ float sh[128];             // [0..63]=gapG, [64..127]=gapS
  __shared__ float wred[2];
  const int p = blockIdx.x;             // 0..1023
  const int t = threadIdx.x;            // 0..127
  sh[t] = ws[WS_GAPS + p * 128 + t];
  __syncthreads();
  float fG = blg[t];
#pragma unroll 8
  for (int i = 0; i < 64; ++i)
    fG = fmaf(sh[i], ws[WS_WLT + i * OUTF + t], fG);
  float fS = blg[t];
#pragma unroll 8
  for (int i = 0; i < 64; ++i)
    fS = fmaf(sh[64 + i], ws[WS_WLT + i * OUTF + t], fS);
  float d = fS - fG;
  float dd = d * d;
  dd += __shfl_down(dd, 32, 64);
  dd += __shfl_down(dd, 16, 64);
  dd += __shfl_down(dd, 8, 64);
  dd += __shfl_down(dd, 4, 64);
  dd += __shfl_down(dd, 2, 64);
  dd += __shfl_down(dd, 1, 64);
  if ((t & 63) == 0) wred[t >> 6] = dd;
  __syncthreads();
  if (t == 0) {
    float s = (wred[0] + wred[1]) + (0.0f + 0.0f);   // baseline tree shape
    atomicAdd(out, s * (1.0f / 131072.0f));
  }
}

extern "C" void kernel_launch(void* const* d_in, const int* in_sizes, int n_in,
                              void* d_out, int out_size, void* d_ws, size_t ws_size,
                              hipStream_t stream) {
  const float* imgG = (const float*)d_in[0];
  const float* imgS = (const float*)d_in[1];
  const float* kpG  = (const float*)d_in[2];
  const float* kpS  = (const float*)d_in[3];
  const float* w1   = (const float*)d_in[4];
  const float* b1   = (const float*)d_in[5];
  const float* w2   = (const float*)d_in[6];
  const float* b2   = (const float*)d_in[7];
  const float* wl   = (const float*)d_in[8];
  const float* bl   = (const float*)d_in[9];
  float* ws  = (float*)d_ws;
  float* out = (float*)d_out;

  hipLaunchKernelGGL(prep_kernel, dim3(32), dim3(256), 0, stream, w1, w2, wl, ws, out);
  hipLaunchKernelGGL(patch_cnn_kernel, dim3(2048), dim3(256), 0, stream,
                     imgG, imgS, kpG, kpS, b1, b2, ws);
  hipLaunchKernelGGL(loss_kernel, dim3(1024), dim3(128), 0, stream, ws, bl, out);
}

// Round 4
// 154.058 us; speedup vs baseline: 1.1256x; 1.1256x over previous
//
#include <hip/hip_runtime.h>

// Problem constants (fixed by setup_inputs)
#define HW   256
#define Pp   33
#define PPAD 36        // padded patch row (ushort units)
#define OUTF 128
#define SIG  16

// conv1-output plane (bf16) for conv2 MFMA A-operands:
// [rowslot 6][parity 2][col' 16][kc 40] ushort.
#define KCP   40
#define PLROW (2 * 16 * KCP)
#define PLSZ  (6 * PLROW)        // 7680 shorts
#define IMS   40                 // im2col k-stride (shorts); 80B rows, b128-aligned

// ws layout (float offsets)
#define WS_W1FH 0       // [2 nt][64 lane][8 j] ushort = 512 f (conv1 B-frags hi)
#define WS_W1FL 512     // same, lo
#define WS_BHI  1024    // 18432 ushort = 9216 f (conv2 B-frags hi)
#define WS_BLO  10240   // conv2 B-frags lo
#define WS_WLT  19456   // [64][128] f32 = 8192

typedef __attribute__((ext_vector_type(8))) short v8s;    // 8 bf16
typedef __attribute__((ext_vector_type(4))) float f32x4;  // MFMA acc

__device__ __forceinline__ unsigned short f2bf_rne(float x) {
  unsigned u = __float_as_uint(x);
  unsigned r = (u + 0x7FFFu + ((u >> 16) & 1u)) >> 16;
  return (unsigned short)r;
}
__device__ __forceinline__ float bf2f(unsigned short h) {
  return __uint_as_float(((unsigned)h) << 16);
}

__global__ __launch_bounds__(256) void prep_kernel(
    const float* __restrict__ w1, const float* __restrict__ w2,
    const float* __restrict__ wl, float* __restrict__ ws,
    float* __restrict__ out) {
  int t = blockIdx.x * 256 + threadIdx.x;
  int stride = gridDim.x * 256;
  if (blockIdx.x == 0 && threadIdx.x == 0) out[0] = 0.0f;
  // conv1 B-frags: k = 8*(l>>4)+j (27-dim padded to 32), ch = 16*nt + (l&15)
  unsigned short* w1h = (unsigned short*)(ws + WS_W1FH);
  unsigned short* w1lo = (unsigned short*)(ws + WS_W1FL);
  for (int i = t; i < 1024; i += stride) {
    int j  = i & 7;
    int l  = (i >> 3) & 63;
    int nt = i >> 9;
    int k  = 8 * (l >> 4) + j;
    int ch = 16 * nt + (l & 15);
    float v = (k < 27) ? w1[ch * 27 + k] : 0.0f;
    unsigned short h = f2bf_rne(v);
    w1h[i]  = h;
    w1lo[i] = f2bf_rne(v - bf2f(h));
  }
  // conv2 B-frags (unchanged): n(ch)=w*16+(l&15), k(kc)=(l>>4)*8+j, per tap
  unsigned short* bhi = (unsigned short*)(ws + WS_BHI);
  unsigned short* blo = (unsigned short*)(ws + WS_BLO);
  for (int i = t; i < 18432; i += stride) {
    int j  = i & 7;
    int l  = (i >> 3) & 63;
    int w  = (i >> 9) & 3;
    int tp = i >> 11;
    int ch = w * 16 + (l & 15);
    int kc = ((l >> 4) << 3) + j;
    int ky = tp / 3, kx = tp - ky * 3;
    float v = w2[ch * 288 + kc * 9 + ky * 3 + kx];
    unsigned short h = f2bf_rne(v);
    bhi[i] = h;
    blo[i] = f2bf_rne(v - bf2f(h));
  }
  for (int i = t; i < 8192; i += stride) {
    int o = i & 127, ii = i >> 7;
    ws[WS_WLT + i] = wl[o * 64 + ii];
  }
}

// One block per (n,b); both sides in-block; one atomicAdd.
// R4 change vs the verified 87us baseline (R0): the 18 conv2 B-fragments
// (side- and loop-invariant, 288B/wave) are preloaded ONCE into registers
// before the side loop, instead of being re-read from L2 18x per y2 iteration.
// Removes the dominant exposed-latency source (L2 ~200cyc per batch, several
// batches per iteration at VGPR=76). Everything else is IDENTICAL to R0:
// same 3-barrier produce_pair schedule, same op-order numerics (absmax 0.0).
__global__ __launch_bounds__(256) void patch_cnn_kernel(
    const float* __restrict__ imgG, const float* __restrict__ imgS,
    const float* __restrict__ kpG,  const float* __restrict__ kpS,
    const float* __restrict__ b1g,  const float* __restrict__ b2g,
    const float* __restrict__ blg,  const float* __restrict__ ws,
    float* __restrict__ out) {
  __shared__ __align__(16) unsigned short patch[3 * Pp * PPAD];  // 7128 B
  __shared__ __align__(16) unsigned short imcol[2][32 * IMS];    // 5120 B
  __shared__ __align__(16) unsigned short hiP[PLSZ];             // 15360 B
  __shared__ float gapv[64];
  __shared__ float fstash[OUTF];
  __shared__ float lred[4];
  // total ~= 28.6 KB

  const int bid  = blockIdx.x;          // grid 1024
  const int n    = bid >> 2;
  const int b    = bid & 3;
  const int tid  = threadIdx.x;
  const int wave = tid >> 6;
  const int lane = tid & 63;

  const int m16 = lane & 15;
  const int qq  = lane >> 4;
  const int mt  = wave & 1;             // conv1 M-tile
  const int nt  = wave >> 1;            // conv1 N-tile

  // im2col build roles: thread = m(32) x k-quad(8)
  const int bm = tid & 31;
  const int kq = tid >> 5;
  int  boff[4];
  bool bval[4];
#pragma unroll
  for (int j = 0; j < 4; ++j) {
    int k = 4 * kq + j;
    bval[j] = (k < 27);
    int kk = bval[j] ? k : 0;
    int ci = kk / 9, r2 = kk - ci * 9, ky = r2 / 3, kx = r2 - ky * 3;
    boff[j] = (ci * Pp + ky) * PPAD + bm + kx;    // + r*PPAD at use
  }

  // conv1 B-frags -> registers (8 VGPRs each), bias per lane
  const v8s w1hF = ((const v8s*)((const unsigned short*)(ws + WS_W1FH)))[nt * 64 + lane];
  const v8s w1lF = ((const v8s*)((const unsigned short*)(ws + WS_W1FL)))[nt * 64 + lane];
  const float b1v = b1g[nt * 16 + m16];

  // conv2 B-frags: preload ALL 18 (hi+lo x 9 taps) into registers once.
  // Constant-indexed in fully-unrolled loops -> stays in VGPRs (72 VGPRs).
  const v8s* bhW = (const v8s*)((const unsigned short*)(ws + WS_BHI)) + (wave * 64 + lane);
  const v8s* blW = (const v8s*)((const unsigned short*)(ws + WS_BLO)) + (wave * 64 + lane);
  v8s bhr[9], blr[9];
#pragma unroll
  for (int tp = 0; tp < 9; ++tp) {
    bhr[tp] = bhW[tp * 256];
    blr[tp] = blW[tp * 256];
  }
  const float b2v = b2g[wave * 16 + m16];

  auto build_row = [&](int r, int ibuf) {
    unsigned short h[4];
#pragma unroll
    for (int j = 0; j < 4; ++j)
      h[j] = bval[j] ? patch[boff[j] + r * PPAD] : (unsigned short)0;
    unsigned w0 = (unsigned)h[0] | ((unsigned)h[1] << 16);
    unsigned w1_ = (unsigned)h[2] | ((unsigned)h[3] << 16);
    *(uint2*)&imcol[ibuf][bm * IMS + 4 * kq] = make_uint2(w0, w1_);
  };

  auto conv1_row = [&](int ibuf, int sl) {
    v8s af = *(const v8s*)&imcol[ibuf][(16 * mt + m16) * IMS + 8 * qq];
    f32x4 a1 = {0.f, 0.f, 0.f, 0.f};
    a1 = __builtin_amdgcn_mfma_f32_16x16x32_bf16(af, w1hF, a1, 0, 0, 0);
    a1 = __builtin_amdgcn_mfma_f32_16x16x32_bf16(af, w1lF, a1, 0, 0, 0);
#pragma unroll
    for (int rg = 0; rg < 4; ++rg) {
      int x = 16 * mt + 4 * qq + rg;      // pixel col (x=31 garbage, masked later)
      float f = fmaxf(a1[rg] + b1v, 0.f);
      hiP[((sl * 2 + (x & 1)) * 16 + (x >> 1)) * KCP + 16 * nt + m16] = f2bf_rne(f);
    }
  };

  auto produce_pair = [&](int r0) {
    const int rB = min(r0 + 1, 30);       // row 31 invalid -> dup row 30 (unread slot)
    int s0p = r0 % 6;
    int s1p = s0p + 1; if (s1p >= 6) s1p -= 6;
    __syncthreads();                      // prior imcol reads done; patch ready
    build_row(r0, 0);
    build_row(rB, 1);
    __syncthreads();                      // imcol visible
    conv1_row(0, s0p);
    conv1_row(1, s1p);
  };

  float dd = 0.0f;

#pragma unroll 1
  for (int side = 0; side < 2; ++side) {
    const float* img = side ? imgS : imgG;
    const float* kp  = side ? kpS : kpG;

    int sx = (int)floorf(kp[n * 2 + 0] * 256.0f) - SIG;
    int sy = (int)floorf(kp[n * 2 + 1] * 256.0f) - SIG;
    sx = min(max(sx, 0), HW - Pp);
    sy = min(max(sy, 0), HW - Pp);

    // stage patch as bf16 pairs (coalesced float2 global reads)
    for (int i = tid; i < (3 * Pp * PPAD) / 2; i += 256) {
      int e  = 2 * i;
      int ci = e / (Pp * PPAD);
      int r2 = e - ci * (Pp * PPAD);
      int r  = r2 / PPAD;
      int cc = r2 - r * PPAD;
      float vx = 0.f, vy = 0.f;
      const float* rowp = &img[((b * 3 + ci) * HW + (sy + r)) * HW + sx];
      if (cc < 32) { float2 v = *(const float2*)(rowp + cc); vx = v.x; vy = v.y; }
      else if (cc == 32) { vx = rowp[32]; }
      unsigned pk = (unsigned)f2bf_rne(vx) | ((unsigned)f2bf_rne(vy) << 16);
      *(unsigned*)&patch[e] = pk;
    }
    // produce_pair's leading barrier orders staging -> build
    produce_pair(0);     // rows 0,1 -> slots 0,1
    produce_pair(2);     // rows 2,3 -> slots 2,3

    float gapAcc = 0.0f;
    int s0 = 0;
#pragma unroll 1
    for (int y2 = 0; y2 < 15; ++y2) {
      __syncthreads();   // conv1 hiP writes visible
      f32x4 acc = {0.f, 0.f, 0.f, 0.f};
#pragma unroll
      for (int ky = 0; ky < 3; ++ky) {
        int sk = s0 + ky; if (sk >= 6) sk -= 6;
#pragma unroll
        for (int kx = 0; kx < 3; ++kx) {
          const int p = kx & 1;
          int cp = m16 + (kx >> 1); if (cp > 15) cp = 15;
          const int idx = ((sk * 2 + p) * 16 + cp) * KCP + qq * 8;
          v8s ah = *(const v8s*)&hiP[idx];
          const int tp = ky * 3 + kx;
          acc = __builtin_amdgcn_mfma_f32_16x16x32_bf16(ah, bhr[tp], acc, 0, 0, 0);
          acc = __builtin_amdgcn_mfma_f32_16x16x32_bf16(ah, blr[tp], acc, 0, 0, 0);
        }
      }
      {
        float s = fmaxf(acc.x + b2v, 0.f) + fmaxf(acc.y + b2v, 0.f) +
                  fmaxf(acc.z + b2v, 0.f);
        if (qq < 3) s += fmaxf(acc.w + b2v, 0.f);   // xout=15 is pad
        gapAcc += s;
      }
      const int r0 = 2 * y2 + 4;
      if (r0 <= 30) produce_pair(r0);
      s0 += 2; if (s0 >= 6) s0 -= 6;
    }

    // reduce gapAcc over kc-quads
    gapAcc += __shfl_down(gapAcc, 32, 64);
    gapAcc += __shfl_down(gapAcc, 16, 64);
    if (lane < 16) gapv[wave * 16 + m16] = gapAcc * (1.0f / 225.0f);
    __syncthreads();

    if (tid < OUTF) {
      float f = blg[tid];
#pragma unroll 8
      for (int i = 0; i < 64; ++i) f = fmaf(gapv[i], ws[WS_WLT + i * OUTF + tid], f);
      if (side == 0) fstash[tid] = f;
      else { float d = f - fstash[tid]; dd = d * d; }
    }
    __syncthreads();
  }

  // block reduction -> one atomicAdd
  dd += __shfl_down(dd, 32, 64);
  dd += __shfl_down(dd, 16, 64);
  dd += __shfl_down(dd, 8, 64);
  dd += __shfl_down(dd, 4, 64);
  dd += __shfl_down(dd, 2, 64);
  dd += __shfl_down(dd, 1, 64);
  if (lane == 0) lred[wave] = dd;
  __syncthreads();
  if (tid == 0) {
    float s = (lred[0] + lred[1]) + (lred[2] + lred[3]);
    atomicAdd(out, s * (1.0f / 131072.0f));
  }
}

extern "C" void kernel_launch(void* const* d_in, const int* in_sizes, int n_in,
                              void* d_out, int out_size, void* d_ws, size_t ws_size,
                              hipStream_t stream) {
  const float* imgG = (const float*)d_in[0];
  const float* imgS = (const float*)d_in[1];
  const float* kpG  = (const float*)d_in[2];
  const float* kpS  = (const float*)d_in[3];
  const float* w1   = (const float*)d_in[4];
  const float* b1   = (const float*)d_in[5];
  const float* w2   = (const float*)d_in[6];
  const float* b2   = (const float*)d_in[7];
  const float* wl   = (const float*)d_in[8];
  const float* bl   = (const float*)d_in[9];
  float* ws  = (float*)d_ws;
  float* out = (float*)d_out;

  hipLaunchKernelGGL(prep_kernel, dim3(32), dim3(256), 0, stream, w1, w2, wl, ws, out);
  hipLaunchKernelGGL(patch_cnn_kernel, dim3(1024), dim3(256), 0, stream,
                     imgG, imgS, kpG, kpS, b1, b2, bl, ws, out);
}

// Round 5
// 149.452 us; speedup vs baseline: 1.1603x; 1.0308x over previous
//
#include <hip/hip_runtime.h>

// Problem constants (fixed by setup_inputs)
#define HW   256
#define Pp   33
#define PPAD 36        // padded patch row (ushort units)
#define OUTF 128
#define SIG  16

// conv1-output plane (bf16) for conv2 MFMA A-operands:
// [rowslot 8][parity 2][col' 16][kc 40] ushort.  8-slot ring (was 6) to allow
// two conv2 rows per iteration.
#define KCP   40
#define PLROW (2 * 16 * KCP)
#define PLSZ  (8 * PLROW)        // 10240 shorts
#define IMS   40                 // im2col k-stride (shorts); 80B rows, b128-aligned

// ws layout (float offsets)
#define WS_W1FH 0       // [2 nt][64 lane][8 j] ushort = 512 f (conv1 B-frags hi)
#define WS_W1FL 512     // same, lo
#define WS_BHI  1024    // 18432 ushort = 9216 f (conv2 B-frags hi)
#define WS_BLO  10240   // conv2 B-frags lo
#define WS_WLT  19456   // [64][128] f32 = 8192

typedef __attribute__((ext_vector_type(8))) short v8s;    // 8 bf16
typedef __attribute__((ext_vector_type(4))) float f32x4;  // MFMA acc

__device__ __forceinline__ unsigned short f2bf_rne(float x) {
  unsigned u = __float_as_uint(x);
  unsigned r = (u + 0x7FFFu + ((u >> 16) & 1u)) >> 16;
  return (unsigned short)r;
}
__device__ __forceinline__ float bf2f(unsigned short h) {
  return __uint_as_float(((unsigned)h) << 16);
}

__global__ __launch_bounds__(256) void prep_kernel(
    const float* __restrict__ w1, const float* __restrict__ w2,
    const float* __restrict__ wl, float* __restrict__ ws,
    float* __restrict__ out) {
  int t = blockIdx.x * 256 + threadIdx.x;
  int stride = gridDim.x * 256;
  if (blockIdx.x == 0 && threadIdx.x == 0) out[0] = 0.0f;
  // conv1 B-frags: k = 8*(l>>4)+j (27-dim padded to 32), ch = 16*nt + (l&15)
  unsigned short* w1h = (unsigned short*)(ws + WS_W1FH);
  unsigned short* w1lo = (unsigned short*)(ws + WS_W1FL);
  for (int i = t; i < 1024; i += stride) {
    int j  = i & 7;
    int l  = (i >> 3) & 63;
    int nt = i >> 9;
    int k  = 8 * (l >> 4) + j;
    int ch = 16 * nt + (l & 15);
    float v = (k < 27) ? w1[ch * 27 + k] : 0.0f;
    unsigned short h = f2bf_rne(v);
    w1h[i]  = h;
    w1lo[i] = f2bf_rne(v - bf2f(h));
  }
  // conv2 B-frags: n(ch)=w*16+(l&15), k(kc)=(l>>4)*8+j, per tap
  unsigned short* bhi = (unsigned short*)(ws + WS_BHI);
  unsigned short* blo = (unsigned short*)(ws + WS_BLO);
  for (int i = t; i < 18432; i += stride) {
    int j  = i & 7;
    int l  = (i >> 3) & 63;
    int w  = (i >> 9) & 3;
    int tp = i >> 11;
    int ch = w * 16 + (l & 15);
    int kc = ((l >> 4) << 3) + j;
    int ky = tp / 3, kx = tp - ky * 3;
    float v = w2[ch * 288 + kc * 9 + ky * 3 + kx];
    unsigned short h = f2bf_rne(v);
    bhi[i] = h;
    blo[i] = f2bf_rne(v - bf2f(h));
  }
  for (int i = t; i < 8192; i += stride) {
    int o = i & 127, ii = i >> 7;
    ws[WS_WLT + i] = wl[o * 64 + ii];
  }
}

// One block per (n,b); both sides in-block; one atomicAdd.  R5 change vs the
// verified R0 schedule: TWO conv2 output rows per main-loop iteration as two
// INDEPENDENT accumulator chains (accA=row 2i, accB=row 2i+1), interleaved
// per-instruction.  Each chain's op order is exactly the baseline's (tap 0..8,
// hi then lo, single chained acc) -> bit-exact numerics, but MFMA dependency
// stalls are halved and barriers drop from 3/row to 1/row.  hiP becomes an
// 8-slot ring; conv1 produces 4 rows/iteration into imcol[4].  Hazard audit:
// iter i reads rows 4i..4i+4 (pre mid-barrier), writes rows 4i+6..4i+9 (post
// mid-barrier); row r vs r+8 slot collisions are read-before-write within one
// iteration, ordered by the mid barrier; cross-iteration RAW ordered by the
// loop-top barrier.
__global__ __launch_bounds__(256) void patch_cnn_kernel(
    const float* __restrict__ imgG, const float* __restrict__ imgS,
    const float* __restrict__ kpG,  const float* __restrict__ kpS,
    const float* __restrict__ b1g,  const float* __restrict__ b2g,
    const float* __restrict__ blg,  const float* __restrict__ ws,
    float* __restrict__ out) {
  __shared__ __align__(16) unsigned short patch[3 * Pp * PPAD];  // 7128 B
  __shared__ __align__(16) unsigned short imcol[4][32 * IMS];    // 10240 B
  __shared__ __align__(16) unsigned short hiP[PLSZ];             // 20480 B
  __shared__ float gapv[64];
  __shared__ float fstash[OUTF];
  __shared__ float lred[4];
  // total ~= 38.6 KB -> 4 blocks/CU by LDS

  const int bid  = blockIdx.x;          // grid 1024
  const int n    = bid >> 2;
  const int b    = bid & 3;
  const int tid  = threadIdx.x;
  const int wave = tid >> 6;
  const int lane = tid & 63;

  const int m16 = lane & 15;
  const int qq  = lane >> 4;
  const int mt  = wave & 1;             // conv1 M-tile
  const int nt  = wave >> 1;            // conv1 N-tile

  // im2col build roles: thread = m(32) x k-quad(8)
  const int bm = tid & 31;
  const int kq = tid >> 5;
  int  boff[4];
  bool bval[4];
#pragma unroll
  for (int j = 0; j < 4; ++j) {
    int k = 4 * kq + j;
    bval[j] = (k < 27);
    int kk = bval[j] ? k : 0;
    int ci = kk / 9, r2 = kk - ci * 9, ky = r2 / 3, kx = r2 - ky * 3;
    boff[j] = (ci * Pp + ky) * PPAD + bm + kx;    // + r*PPAD at use
  }

  // conv1 B-frags -> registers (8 VGPRs each), bias per lane
  const v8s w1hF = ((const v8s*)((const unsigned short*)(ws + WS_W1FH)))[nt * 64 + lane];
  const v8s w1lF = ((const v8s*)((const unsigned short*)(ws + WS_W1FL)))[nt * 64 + lane];
  const float b1v = b1g[nt * 16 + m16];

  // conv2 frag pointers (L2-resident) and bias
  const v8s* bhW = (const v8s*)((const unsigned short*)(ws + WS_BHI)) + (wave * 64 + lane);
  const v8s* blW = (const v8s*)((const unsigned short*)(ws + WS_BLO)) + (wave * 64 + lane);
  const float b2v = b2g[wave * 16 + m16];

  auto build_row = [&](int r, int ibuf) {
    unsigned short h[4];
#pragma unroll
    for (int j = 0; j < 4; ++j)
      h[j] = bval[j] ? patch[boff[j] + r * PPAD] : (unsigned short)0;
    unsigned w0 = (unsigned)h[0] | ((unsigned)h[1] << 16);
    unsigned w1_ = (unsigned)h[2] | ((unsigned)h[3] << 16);
    *(uint2*)&imcol[ibuf][bm * IMS + 4 * kq] = make_uint2(w0, w1_);
  };

  auto conv1_row = [&](int ibuf, int sl) {
    v8s af = *(const v8s*)&imcol[ibuf][(16 * mt + m16) * IMS + 8 * qq];
    f32x4 a1 = {0.f, 0.f, 0.f, 0.f};
    a1 = __builtin_amdgcn_mfma_f32_16x16x32_bf16(af, w1hF, a1, 0, 0, 0);
    a1 = __builtin_amdgcn_mfma_f32_16x16x32_bf16(af, w1lF, a1, 0, 0, 0);
#pragma unroll
    for (int rg = 0; rg < 4; ++rg) {
      int x = 16 * mt + 4 * qq + rg;      // pixel col (x=31 garbage, unread slot)
      float f = fmaxf(a1[rg] + b1v, 0.f);
      hiP[((sl * 2 + (x & 1)) * 16 + (x >> 1)) * KCP + 16 * nt + m16] = f2bf_rne(f);
    }
  };

  // conv2 A-operand load: (row-slot sk in [0,8), tap kx)
  auto ldA = [&](int sk, int kx) -> v8s {
    const int p = kx & 1;
    int cp = m16 + (kx >> 1); if (cp > 15) cp = 15;   // xo=15 is pad, discarded
    return *(const v8s*)&hiP[((sk * 2 + p) * 16 + cp) * KCP + qq * 8];
  };

// dual-row tap: chain order inside each acc identical to baseline (hi, lo)
#define TAP2(tp, aA, aB)                                                      \
  { v8s bh_ = bhW[(tp) * 256]; v8s bl_ = blW[(tp) * 256];                     \
    accA = __builtin_amdgcn_mfma_f32_16x16x32_bf16(aA, bh_, accA, 0, 0, 0);   \
    accB = __builtin_amdgcn_mfma_f32_16x16x32_bf16(aB, bh_, accB, 0, 0, 0);   \
    accA = __builtin_amdgcn_mfma_f32_16x16x32_bf16(aA, bl_, accA, 0, 0, 0);   \
    accB = __builtin_amdgcn_mfma_f32_16x16x32_bf16(aB, bl_, accB, 0, 0, 0); }
#define TAP1(tp, aa)                                                          \
  { v8s bh_ = bhW[(tp) * 256]; v8s bl_ = blW[(tp) * 256];                     \
    acc = __builtin_amdgcn_mfma_f32_16x16x32_bf16(aa, bh_, acc, 0, 0, 0);     \
    acc = __builtin_amdgcn_mfma_f32_16x16x32_bf16(aa, bl_, acc, 0, 0, 0); }

  float dd = 0.0f;

#pragma unroll 1
  for (int side = 0; side < 2; ++side) {
    const float* img = side ? imgS : imgG;
    const float* kp  = side ? kpS : kpG;

    int sx = (int)floorf(kp[n * 2 + 0] * 256.0f) - SIG;
    int sy = (int)floorf(kp[n * 2 + 1] * 256.0f) - SIG;
    sx = min(max(sx, 0), HW - Pp);
    sy = min(max(sy, 0), HW - Pp);

    // stage patch as bf16 pairs (coalesced float2 global reads)
    for (int i = tid; i < (3 * Pp * PPAD) / 2; i += 256) {
      int e  = 2 * i;
      int ci = e / (Pp * PPAD);
      int r2 = e - ci * (Pp * PPAD);
      int r  = r2 / PPAD;
      int cc = r2 - r * PPAD;
      float vx = 0.f, vy = 0.f;
      const float* rowp = &img[((b * 3 + ci) * HW + (sy + r)) * HW + sx];
      if (cc < 32) { float2 v = *(const float2*)(rowp + cc); vx = v.x; vy = v.y; }
      else if (cc == 32) { vx = rowp[32]; }
      unsigned pk = (unsigned)f2bf_rne(vx) | ((unsigned)f2bf_rne(vy) << 16);
      *(unsigned*)&patch[e] = pk;
    }
    __syncthreads();                    // patch visible
    // prologue: rows 0..5 -> slots 0..5
    build_row(0, 0); build_row(1, 1); build_row(2, 2); build_row(3, 3);
    __syncthreads();                    // imcol visible
    conv1_row(0, 0); conv1_row(1, 1); conv1_row(2, 2); conv1_row(3, 3);
    __syncthreads();                    // conv1 imcol reads done before rebuild
    build_row(4, 0); build_row(5, 1);
    __syncthreads();
    conv1_row(0, 4); conv1_row(1, 5);

    float gapAcc = 0.0f;

#pragma unroll 1
    for (int i = 0; i < 7; ++i) {       // y2 = 2i, 2i+1
      __syncthreads();                  // hiP rows 4i..4i+5 visible
      const int s0 = (4 * i)     & 7;
      const int s1 = (4 * i + 1) & 7;
      const int s2 = (4 * i + 2) & 7;   // shared row (A:ky=2, B:ky=0)
      const int s3 = (4 * i + 3) & 7;
      const int s4 = (4 * i + 4) & 7;
      f32x4 accA = {0.f, 0.f, 0.f, 0.f};
      f32x4 accB = {0.f, 0.f, 0.f, 0.f};
      v8s sh0 = ldA(s2, 0), sh1 = ldA(s2, 1), sh2 = ldA(s2, 2);
      {
        v8s a0 = ldA(s0, 0), a1 = ldA(s0, 1), a2 = ldA(s0, 2);
        TAP2(0, a0, sh0); TAP2(1, a1, sh1); TAP2(2, a2, sh2);
      }
      {
        v8s a0 = ldA(s1, 0), a1 = ldA(s1, 1), a2 = ldA(s1, 2);
        v8s b0 = ldA(s3, 0), b1 = ldA(s3, 1), b2 = ldA(s3, 2);
        TAP2(3, a0, b0); TAP2(4, a1, b1); TAP2(5, a2, b2);
      }
      {
        v8s b0 = ldA(s4, 0), b1 = ldA(s4, 1), b2 = ldA(s4, 2);
        TAP2(6, sh0, b0); TAP2(7, sh1, b1); TAP2(8, sh2, b2);
      }

      // produce conv1 rows 4i+6 .. 4i+9 (guarded; rows >30 don't exist)
      const int r0 = 4 * i + 6;
      if (r0     <= 30) build_row(r0,     0);
      if (r0 + 1 <= 30) build_row(r0 + 1, 1);
      if (r0 + 2 <= 30) build_row(r0 + 2, 2);
      if (r0 + 3 <= 30) build_row(r0 + 3, 3);
      __syncthreads();                  // imcol visible; conv2 hiP reads done
      if (r0     <= 30) conv1_row(0, r0 & 7);
      if (r0 + 1 <= 30) conv1_row(1, (r0 + 1) & 7);
      if (r0 + 2 <= 30) conv1_row(2, (r0 + 2) & 7);
      if (r0 + 3 <= 30) conv1_row(3, (r0 + 3) & 7);

      // gap accumulate in baseline order: s(2i) then s(2i+1)
      {
        float sA = fmaxf(accA.x + b2v, 0.f) + fmaxf(accA.y + b2v, 0.f) +
                   fmaxf(accA.z + b2v, 0.f);
        if (qq < 3) sA += fmaxf(accA.w + b2v, 0.f);
        gapAcc += sA;
        float sB = fmaxf(accB.x + b2v, 0.f) + fmaxf(accB.y + b2v, 0.f) +
                   fmaxf(accB.z + b2v, 0.f);
        if (qq < 3) sB += fmaxf(accB.w + b2v, 0.f);
        gapAcc += sB;
      }
    }

    // tail: y2 = 14 (rows 28,29,30 -> slots 4,5,6), baseline single chain
    {
      __syncthreads();
      f32x4 acc = {0.f, 0.f, 0.f, 0.f};
      v8s a0 = ldA(4, 0), a1 = ldA(4, 1), a2 = ldA(4, 2);
      TAP1(0, a0); TAP1(1, a1); TAP1(2, a2);
      v8s c0 = ldA(5, 0), c1 = ldA(5, 1), c2 = ldA(5, 2);
      TAP1(3, c0); TAP1(4, c1); TAP1(5, c2);
      v8s e0 = ldA(6, 0), e1 = ldA(6, 1), e2 = ldA(6, 2);
      TAP1(6, e0); TAP1(7, e1); TAP1(8, e2);
      float s = fmaxf(acc.x + b2v, 0.f) + fmaxf(acc.y + b2v, 0.f) +
                fmaxf(acc.z + b2v, 0.f);
      if (qq < 3) s += fmaxf(acc.w + b2v, 0.f);
      gapAcc += s;
    }

    // reduce gapAcc over kc-quads
    gapAcc += __shfl_down(gapAcc, 32, 64);
    gapAcc += __shfl_down(gapAcc, 16, 64);
    if (lane < 16) gapv[wave * 16 + m16] = gapAcc * (1.0f / 225.0f);
    __syncthreads();

    if (tid < OUTF) {
      float f = blg[tid];
#pragma unroll 8
      for (int i = 0; i < 64; ++i) f = fmaf(gapv[i], ws[WS_WLT + i * OUTF + tid], f);
      if (side == 0) fstash[tid] = f;
      else { float d = f - fstash[tid]; dd = d * d; }
    }
    __syncthreads();
  }

  // block reduction -> one atomicAdd
  dd += __shfl_down(dd, 32, 64);
  dd += __shfl_down(dd, 16, 64);
  dd += __shfl_down(dd, 8, 64);
  dd += __shfl_down(dd, 4, 64);
  dd += __shfl_down(dd, 2, 64);
  dd += __shfl_down(dd, 1, 64);
  if (lane == 0) lred[wave] = dd;
  __syncthreads();
  if (tid == 0) {
    float s = (lred[0] + lred[1]) + (lred[2] + lred[3]);
    atomicAdd(out, s * (1.0f / 131072.0f));
  }
}

extern "C" void kernel_launch(void* const* d_in, const int* in_sizes, int n_in,
                              void* d_out, int out_size, void* d_ws, size_t ws_size,
                              hipStream_t stream) {
  const float* imgG = (const float*)d_in[0];
  const float* imgS = (const float*)d_in[1];
  const float* kpG  = (const float*)d_in[2];
  const float* kpS  = (const float*)d_in[3];
  const float* w1   = (const float*)d_in[4];
  const float* b1   = (const float*)d_in[5];
  const float* w2   = (const float*)d_in[6];
  const float* b2   = (const float*)d_in[7];
  const float* wl   = (const float*)d_in[8];
  const float* bl   = (const float*)d_in[9];
  float* ws  = (float*)d_ws;
  float* out = (float*)d_out;

  hipLaunchKernelGGL(prep_kernel, dim3(32), dim3(256), 0, stream, w1, w2, wl, ws, out);
  hipLaunchKernelGGL(patch_cnn_kernel, dim3(1024), dim3(256), 0, stream,
                     imgG, imgS, kpG, kpS, b1, b2, bl, ws, out);
}

// Round 6
// 143.348 us; speedup vs baseline: 1.2097x; 1.0426x over previous
//
#include <hip/hip_runtime.h>

// Problem constants (fixed by setup_inputs)
#define HW   256
#define Pp   33
#define PPAD 36        // padded patch row (ushort units)
#define OUTF 128
#define SIG  16

// conv1-output plane (bf16) for conv2 MFMA A-operands:
// [rowslot NSLOT][parity 2][col' 16][kc 40] ushort.
// 10-slot ring: iter i reads slots (4i..4i+4)%10, writes (4i+6..4i+9)%10 —
// disjoint mod 10 -> NO mid-iteration barrier needed (1 barrier / 2 rows).
#define KCP   40
#define PLROW (2 * 16 * KCP)     // 1280 shorts per conv1 row
#define NSLOT 10
#define PLSZ  (NSLOT * PLROW)    // 12800 shorts = 25600 B

// ws layout (float offsets)
#define WS_W1FH 0       // [2 nt][64 lane][8 j] ushort = 512 f (conv1 B-frags hi)
#define WS_W1FL 512     // same, lo
#define WS_BHI  1024    // 18432 ushort = 9216 f (conv2 B-frags hi)
#define WS_BLO  10240   // conv2 B-frags lo
#define WS_WLT  19456   // [64][128] f32 = 8192

typedef __attribute__((ext_vector_type(8))) short v8s;    // 8 bf16
typedef __attribute__((ext_vector_type(4))) float f32x4;  // MFMA acc

__device__ __forceinline__ unsigned short f2bf_rne(float x) {
  unsigned u = __float_as_uint(x);
  unsigned r = (u + 0x7FFFu + ((u >> 16) & 1u)) >> 16;
  return (unsigned short)r;
}
__device__ __forceinline__ float bf2f(unsigned short h) {
  return __uint_as_float(((unsigned)h) << 16);
}

__global__ __launch_bounds__(256) void prep_kernel(
    const float* __restrict__ w1, const float* __restrict__ w2,
    const float* __restrict__ wl, float* __restrict__ ws,
    float* __restrict__ out) {
  int t = blockIdx.x * 256 + threadIdx.x;
  int stride = gridDim.x * 256;
  if (blockIdx.x == 0 && threadIdx.x == 0) out[0] = 0.0f;
  // conv1 B-frags: k = 8*(l>>4)+j (27-dim padded to 32), ch = 16*nt + (l&15)
  unsigned short* w1h = (unsigned short*)(ws + WS_W1FH);
  unsigned short* w1lo = (unsigned short*)(ws + WS_W1FL);
  for (int i = t; i < 1024; i += stride) {
    int j  = i & 7;
    int l  = (i >> 3) & 63;
    int nt = i >> 9;
    int k  = 8 * (l >> 4) + j;
    int ch = 16 * nt + (l & 15);
    float v = (k < 27) ? w1[ch * 27 + k] : 0.0f;
    unsigned short h = f2bf_rne(v);
    w1h[i]  = h;
    w1lo[i] = f2bf_rne(v - bf2f(h));
  }
  // conv2 B-frags: n(ch)=w*16+(l&15), k(kc)=(l>>4)*8+j, per tap
  unsigned short* bhi = (unsigned short*)(ws + WS_BHI);
  unsigned short* blo = (unsigned short*)(ws + WS_BLO);
  for (int i = t; i < 18432; i += stride) {
    int j  = i & 7;
    int l  = (i >> 3) & 63;
    int w  = (i >> 9) & 3;
    int tp = i >> 11;
    int ch = w * 16 + (l & 15);
    int kc = ((l >> 4) << 3) + j;
    int ky = tp / 3, kx = tp - ky * 3;
    float v = w2[ch * 288 + kc * 9 + ky * 3 + kx];
    unsigned short h = f2bf_rne(v);
    bhi[i] = h;
    blo[i] = f2bf_rne(v - bf2f(h));
  }
  for (int i = t; i < 8192; i += stride) {
    int o = i & 127, ii = i >> 7;
    ws[WS_WLT + i] = wl[o * 64 + ii];
  }
}

// One block per (n,b); both sides in-block; one atomicAdd.
// R6 structure (numerics op-identical to R0/R5, absmax 0.0):
//  - WAVE-LOCAL conv1: each wave owns one conv1 row, gathers its A-fragments
//    directly from patch (16 ds_read_u16 + VALU pack), computes all 4 (mt,nt)
//    tiles, writes hiP. imcol ELIMINATED (no staging write, no b128 re-read,
//    no build->conv1 barrier). Values identical to the old imcol path.
//  - 10-slot hiP ring: conv2 of iter i reads slots (4i..4i+4)%10, conv1
//    writes (4i+6..4i+9)%10 -> disjoint -> ONE barrier per iteration.
//  - cross-iteration A-frag register cache: iter i's s4 row = iter i+1's s0
//    row (ds_read_b128 15 -> 12 per iter); tail reuses the cache.
//  - conv2 dual-row independent chains (TAP2) exactly as R5.
__global__ __launch_bounds__(256) void patch_cnn_kernel(
    const float* __restrict__ imgG, const float* __restrict__ imgS,
    const float* __restrict__ kpG,  const float* __restrict__ kpS,
    const float* __restrict__ b1g,  const float* __restrict__ b2g,
    const float* __restrict__ blg,  const float* __restrict__ ws,
    float* __restrict__ out) {
  __shared__ __align__(16) unsigned short patch[3 * Pp * PPAD];  // 7128 B
  __shared__ __align__(16) unsigned short hiP[PLSZ];             // 25600 B
  __shared__ float gapv[64];
  __shared__ float fstash[OUTF];
  __shared__ float lred[4];
  // total ~= 33.5 KB -> 4 blocks/CU by LDS

  const int bid  = blockIdx.x;          // grid 1024
  const int n    = bid >> 2;
  const int b    = bid & 3;
  const int tid  = threadIdx.x;
  const int wave = tid >> 6;
  const int lane = tid & 63;

  const int m16 = lane & 15;
  const int qq  = lane >> 4;

  // conv1 per-lane gather offsets: A-frag element j -> k = 8*qq + j
  int  koff[8];
  bool kval[8];
#pragma unroll
  for (int j = 0; j < 8; ++j) {
    int k = 8 * qq + j;
    kval[j] = (k < 27);
    int kk = kval[j] ? k : 0;
    int ci = kk / 9, r2 = kk - ci * 9, ky = r2 / 3, kx = r2 - ky * 3;
    koff[j] = (ci * Pp + ky) * PPAD + kx;          // + r*PPAD + pixel at use
  }

  // conv1 B-frags for BOTH nt slices (each wave does all 4 tiles of its row)
  const v8s* w1fp = (const v8s*)((const unsigned short*)(ws + WS_W1FH));
  const v8s* w1lp = (const v8s*)((const unsigned short*)(ws + WS_W1FL));
  const v8s w1hF0 = w1fp[lane],      w1lF0 = w1lp[lane];
  const v8s w1hF1 = w1fp[64 + lane], w1lF1 = w1lp[64 + lane];
  const float b1v0 = b1g[m16];
  const float b1v1 = b1g[16 + m16];

  // conv2 frag pointers (L2-resident) and bias (N-split by wave, as always)
  const v8s* bhW = (const v8s*)((const unsigned short*)(ws + WS_BHI)) + (wave * 64 + lane);
  const v8s* blW = (const v8s*)((const unsigned short*)(ws + WS_BLO)) + (wave * 64 + lane);
  const float b2v = b2g[wave * 16 + m16];

  // wave-local conv1 for row r: gather 2 A-frags from patch, 4 MFMA tiles,
  // 16 b16 hiP writes. Values/op-order identical to the old build+conv1 path.
  auto conv1_row_local = [&](int r) {
    const int sl = r % NSLOT;
    const int rbase = r * PPAD;
#pragma unroll
    for (int mtl = 0; mtl < 2; ++mtl) {
      v8s af;
#pragma unroll
      for (int j = 0; j < 8; ++j) {
        unsigned short v =
            kval[j] ? patch[koff[j] + rbase + 16 * mtl + m16] : (unsigned short)0;
        af[j] = (short)v;
      }
      f32x4 z = {0.f, 0.f, 0.f, 0.f};
      f32x4 t0 = __builtin_amdgcn_mfma_f32_16x16x32_bf16(af, w1hF0, z, 0, 0, 0);
      t0 = __builtin_amdgcn_mfma_f32_16x16x32_bf16(af, w1lF0, t0, 0, 0, 0);
      f32x4 t1 = __builtin_amdgcn_mfma_f32_16x16x32_bf16(af, w1hF1, z, 0, 0, 0);
      t1 = __builtin_amdgcn_mfma_f32_16x16x32_bf16(af, w1lF1, t1, 0, 0, 0);
#pragma unroll
      for (int rg = 0; rg < 4; ++rg) {
        int x = 16 * mtl + 4 * qq + rg;   // x=31 garbage, unread slot
        int rowoff = ((sl * 2 + (x & 1)) * 16 + (x >> 1)) * KCP;
        hiP[rowoff + m16]      = f2bf_rne(fmaxf(t0[rg] + b1v0, 0.f));
        hiP[rowoff + 16 + m16] = f2bf_rne(fmaxf(t1[rg] + b1v1, 0.f));
      }
    }
  };

  // conv2 A-operand load: (row-slot sk in [0,NSLOT), tap kx)
  auto ldA = [&](int sk, int kx) -> v8s {
    const int p = kx & 1;
    int cp = m16 + (kx >> 1); if (cp > 15) cp = 15;   // xo=15 is pad, discarded
    return *(const v8s*)&hiP[((sk * 2 + p) * 16 + cp) * KCP + qq * 8];
  };

// dual-row tap: chain order inside each acc identical to baseline (hi, lo)
#define TAP2(tp, aA, aB)                                                      \
  { v8s bh_ = bhW[(tp) * 256]; v8s bl_ = blW[(tp) * 256];                     \
    accA = __builtin_amdgcn_mfma_f32_16x16x32_bf16(aA, bh_, accA, 0, 0, 0);   \
    accB = __builtin_amdgcn_mfma_f32_16x16x32_bf16(aB, bh_, accB, 0, 0, 0);   \
    accA = __builtin_amdgcn_mfma_f32_16x16x32_bf16(aA, bl_, accA, 0, 0, 0);   \
    accB = __builtin_amdgcn_mfma_f32_16x16x32_bf16(aB, bl_, accB, 0, 0, 0); }
#define TAP1(tp, aa)                                                          \
  { v8s bh_ = bhW[(tp) * 256]; v8s bl_ = blW[(tp) * 256];                     \
    acc = __builtin_amdgcn_mfma_f32_16x16x32_bf16(aa, bh_, acc, 0, 0, 0);     \
    acc = __builtin_amdgcn_mfma_f32_16x16x32_bf16(aa, bl_, acc, 0, 0, 0); }

  float dd = 0.0f;

#pragma unroll 1
  for (int side = 0; side < 2; ++side) {
    const float* img = side ? imgS : imgG;
    const float* kp  = side ? kpS : kpG;

    int sx = (int)floorf(kp[n * 2 + 0] * 256.0f) - SIG;
    int sy = (int)floorf(kp[n * 2 + 1] * 256.0f) - SIG;
    sx = min(max(sx, 0), HW - Pp);
    sy = min(max(sy, 0), HW - Pp);

    // stage patch as bf16 pairs (coalesced float2 global reads)
    for (int i = tid; i < (3 * Pp * PPAD) / 2; i += 256) {
      int e  = 2 * i;
      int ci = e / (Pp * PPAD);
      int r2 = e - ci * (Pp * PPAD);
      int r  = r2 / PPAD;
      int cc = r2 - r * PPAD;
      float vx = 0.f, vy = 0.f;
      const float* rowp = &img[((b * 3 + ci) * HW + (sy + r)) * HW + sx];
      if (cc < 32) { float2 v = *(const float2*)(rowp + cc); vx = v.x; vy = v.y; }
      else if (cc == 32) { vx = rowp[32]; }
      unsigned pk = (unsigned)f2bf_rne(vx) | ((unsigned)f2bf_rne(vy) << 16);
      *(unsigned*)&patch[e] = pk;
    }
    __syncthreads();                    // patch visible
    // prologue: rows 0..5, wave-local (slots 0..5); no barriers needed between
    conv1_row_local(wave);              // rows 0..3
    if (wave < 2) conv1_row_local(4 + wave);  // rows 4,5

    float gapAcc = 0.0f;
    v8s n0, n1, n2;                     // cached s4 row (next iter's s0 / ky0)

#pragma unroll 1
    for (int i = 0; i < 7; ++i) {       // conv2 rows y = 2i, 2i+1
      __syncthreads();                  // hiP rows 4i..4i+5 visible
      const int base = 4 * i;
      const int s1 = (base + 1) % NSLOT;
      const int s2 = (base + 2) % NSLOT;
      const int s3 = (base + 3) % NSLOT;
      const int s4 = (base + 4) % NSLOT;
      if (i == 0) { n0 = ldA(0, 0); n1 = ldA(0, 1); n2 = ldA(0, 2); }
      const v8s a00 = n0, a01 = n1, a02 = n2;       // row 4i (accA ky0)
      f32x4 accA = {0.f, 0.f, 0.f, 0.f};
      f32x4 accB = {0.f, 0.f, 0.f, 0.f};
      v8s sh0 = ldA(s2, 0), sh1 = ldA(s2, 1), sh2 = ldA(s2, 2);  // shared row
      {
        TAP2(0, a00, sh0); TAP2(1, a01, sh1); TAP2(2, a02, sh2);
      }
      {
        v8s r10 = ldA(s1, 0), r11 = ldA(s1, 1), r12 = ldA(s1, 2);
        v8s r30 = ldA(s3, 0), r31 = ldA(s3, 1), r32 = ldA(s3, 2);
        TAP2(3, r10, r30); TAP2(4, r11, r31); TAP2(5, r12, r32);
      }
      {
        n0 = ldA(s4, 0); n1 = ldA(s4, 1); n2 = ldA(s4, 2);  // refill cache
        TAP2(6, sh0, n0); TAP2(7, sh1, n1); TAP2(8, sh2, n2);
      }

      // conv1: wave-local rows 4i+6 .. 4i+9 -> slots disjoint from reads mod 10
      {
        const int r = base + 6 + wave;
        if (r <= 30) conv1_row_local(r);
      }

      // gap accumulate in baseline order: y=2i then y=2i+1
      {
        float sA = fmaxf(accA.x + b2v, 0.f) + fmaxf(accA.y + b2v, 0.f) +
                   fmaxf(accA.z + b2v, 0.f);
        if (qq < 3) sA += fmaxf(accA.w + b2v, 0.f);
        gapAcc += sA;
        float sB = fmaxf(accB.x + b2v, 0.f) + fmaxf(accB.y + b2v, 0.f) +
                   fmaxf(accB.z + b2v, 0.f);
        if (qq < 3) sB += fmaxf(accB.w + b2v, 0.f);
        gapAcc += sB;
      }
    }

    // tail: y = 14 (rows 28,29,30 -> slots 8,9,0); n* holds row 28 already
    {
      __syncthreads();                  // row 30 (slot 0) writes visible
      f32x4 acc = {0.f, 0.f, 0.f, 0.f};
      TAP1(0, n0); TAP1(1, n1); TAP1(2, n2);
      v8s c0 = ldA(9, 0), c1 = ldA(9, 1), c2 = ldA(9, 2);
      TAP1(3, c0); TAP1(4, c1); TAP1(5, c2);
      v8s e0 = ldA(0, 0), e1 = ldA(0, 1), e2 = ldA(0, 2);
      TAP1(6, e0); TAP1(7, e1); TAP1(8, e2);
      float s = fmaxf(acc.x + b2v, 0.f) + fmaxf(acc.y + b2v, 0.f) +
                fmaxf(acc.z + b2v, 0.f);
      if (qq < 3) s += fmaxf(acc.w + b2v, 0.f);
      gapAcc += s;
    }

    // reduce gapAcc over kc-quads
    gapAcc += __shfl_down(gapAcc, 32, 64);
    gapAcc += __shfl_down(gapAcc, 16, 64);
    if (lane < 16) gapv[wave * 16 + m16] = gapAcc * (1.0f / 225.0f);
    __syncthreads();

    if (tid < OUTF) {
      float f = blg[tid];
#pragma unroll 8
      for (int i = 0; i < 64; ++i) f = fmaf(gapv[i], ws[WS_WLT + i * OUTF + tid], f);
      if (side == 0) fstash[tid] = f;
      else { float d = f - fstash[tid]; dd = d * d; }
    }
    __syncthreads();
  }

  // block reduction -> one atomicAdd
  dd += __shfl_down(dd, 32, 64);
  dd += __shfl_down(dd, 16, 64);
  dd += __shfl_down(dd, 8, 64);
  dd += __shfl_down(dd, 4, 64);
  dd += __shfl_down(dd, 2, 64);
  dd += __shfl_down(dd, 1, 64);
  if (lane == 0) lred[wave] = dd;
  __syncthreads();
  if (tid == 0) {
    float s = (lred[0] + lred[1]) + (lred[2] + lred[3]);
    atomicAdd(out, s * (1.0f / 131072.0f));
  }
}

extern "C" void kernel_launch(void* const* d_in, const int* in_sizes, int n_in,
                              void* d_out, int out_size, void* d_ws, size_t ws_size,
                              hipStream_t stream) {
  const float* imgG = (const float*)d_in[0];
  const float* imgS = (const float*)d_in[1];
  const float* kpG  = (const float*)d_in[2];
  const float* kpS  = (const float*)d_in[3];
  const float* w1   = (const float*)d_in[4];
  const float* b1   = (const float*)d_in[5];
  const float* w2   = (const float*)d_in[6];
  const float* b2   = (const float*)d_in[7];
  const float* wl   = (const float*)d_in[8];
  const float* bl   = (const float*)d_in[9];
  float* ws  = (float*)d_ws;
  float* out = (float*)d_out;

  hipLaunchKernelGGL(prep_kernel, dim3(32), dim3(256), 0, stream, w1, w2, wl, ws, out);
  hipLaunchKernelGGL(patch_cnn_kernel, dim3(1024), dim3(256), 0, stream,
                     imgG, imgS, kpG, kpS, b1, b2, bl, ws, out);
}